// Round 2
// baseline (422.689 us; speedup 1.0000x reference)
//
#include <hip/hip_runtime.h>
#include <math.h>

#define BATCH 4
#define HH 512
#define WW 512
#define NPIX (HH*WW)
#define NOBJ 8
#define NPART 16
#define NINST 24
#define KBINS 4096
#define SIGMA_SCALE_C 5.5f

// ws layout (u32 words):
//   [0, HIST_WORDS)                : hist u32 [B][24][2][KBINS]
//   [ACCUM_OFF, +ACCUM_WORDS)      : accum f32 [B][24][5]  (cnt, sx, sy, ssig, ssig2)
//   [PARAMS_OFF, +B*24*4)          : params f32 [B][24][4] (cx, cy, l11, cnt)
#define HIST_WORDS (BATCH*NINST*2*KBINS)
#define ACCUM_WORDS (BATCH*NINST*5)
#define ACCUM_OFF HIST_WORDS
#define PARAMS_OFF (ACCUM_OFF + ACCUM_WORDS)

__device__ __forceinline__ float sigmoidf_(float x){ return 1.0f/(1.0f + expf(-x)); }

__global__ void k_zero(unsigned* __restrict__ ws, float* __restrict__ out){
  const int n = HIST_WORDS + ACCUM_WORDS;
  for (int i = blockIdx.x*blockDim.x + threadIdx.x; i < n; i += gridDim.x*blockDim.x)
    ws[i] = 0u;
  if (blockIdx.x == 0 && threadIdx.x == 0) out[0] = 0.0f;
}

// Stage A: per-instance reductions + background seed losses.
// grid (NPIX/4096, BATCH), block 256
__global__ __launch_bounds__(256) void k_reduce(
    const float* __restrict__ pred, const int* __restrict__ obj_inst,
    const int* __restrict__ obj_lab, const int* __restrict__ parts_inst,
    const int* __restrict__ parts_lab, const float* __restrict__ xym,
    float* __restrict__ accum, float* __restrict__ out){
  __shared__ float acc[NINST*5];
  __shared__ float sbg[2];
  const int tid = threadIdx.x;
  for (int i = tid; i < NINST*5; i += blockDim.x) acc[i] = 0.f;
  if (tid < 2) sbg[tid] = 0.f;
  __syncthreads();
  const int img = blockIdx.y;
  const float* predb = pred + (size_t)img*8*NPIX;
  const int base = blockIdx.x*4096;
  float bgo = 0.f, bgp = 0.f;
  for (int it = 0; it < 16; ++it){
    const int pix = base + it*256 + tid;
    const int idx = img*NPIX + pix;
    const int oid = obj_inst[idx];
    const int pid = parts_inst[idx];
    const float xm = xym[pix], ym = xym[NPIX + pix];
    if (oid >= 1 && oid <= NOBJ){
      const float s = predb[2*NPIX + pix];
      float* a = &acc[(oid-1)*5];
      atomicAdd(a+0, 1.f); atomicAdd(a+1, xm); atomicAdd(a+2, ym);
      atomicAdd(a+3, s);   atomicAdd(a+4, s*s);
    }
    if (pid >= 1 && pid <= NPART){
      const float s = predb[5*NPIX + pix];
      float* a = &acc[(NOBJ + pid - 1)*5];
      atomicAdd(a+0, 1.f); atomicAdd(a+1, xm); atomicAdd(a+2, ym);
      atomicAdd(a+3, s);   atomicAdd(a+4, s*s);
    }
    if (obj_lab[idx] != 1){ const float s = sigmoidf_(predb[6*NPIX + pix]); bgo += s*s; }
    if (parts_lab[idx] != 1){ const float s = sigmoidf_(predb[7*NPIX + pix]); bgp += s*s; }
  }
  for (int off = 32; off > 0; off >>= 1){
    bgo += __shfl_down(bgo, off);
    bgp += __shfl_down(bgp, off);
  }
  if ((tid & 63) == 0){ atomicAdd(&sbg[0], bgo); atomicAdd(&sbg[1], bgp); }
  __syncthreads();
  if (tid < NINST*5) atomicAdd(&accum[img*NINST*5 + tid], acc[tid]);
  if (tid == 0) atomicAdd(out, (sbg[0] + sbg[1]) * (1.0f/((float)NPIX*BATCH)));
}

// Stage B: per-instance params + variance term. 1 block, 128 threads.
__global__ void k_params(const float* __restrict__ accum, float* __restrict__ params,
                         float* __restrict__ out){
  const int t = threadIdx.x;
  if (t >= BATCH*NINST) return;
  const float* a = accum + t*5;
  const float cnt = a[0];
  float cx = 0.f, cy = 0.f, l11 = 1.f, var = 0.f;
  if (cnt > 0.5f){
    const float inv = 1.0f/cnt;
    cx = a[1]*inv; cy = a[2]*inv;
    const float s = a[3]*inv;
    var = a[4]*inv - s*s;       // == mean((sigma - mean)^2), closed form
    if (var < 0.f) var = 0.f;
    l11 = expf(SIGMA_SCALE_C * s);
  }
  float* p = params + t*4;
  p[0] = cx; p[1] = cy; p[2] = l11; p[3] = cnt;
  const int inst = t % NINST;
  const float wN = (inst < NOBJ) ? (float)NOBJ : (float)NPART;
  if (cnt > 0.5f) atomicAdd(out, var * (10.0f/(wN*BATCH)));
}

// Stage C: per-(img, instance) error histogram + foreground seed loss.
// grid (NINST, NPIX/32768, BATCH), block 256. LDS 32KB hist.
__global__ __launch_bounds__(256) void k_hist(
    const float* __restrict__ pred, const int* __restrict__ obj_inst,
    const int* __restrict__ parts_inst, const float* __restrict__ xym,
    const float* __restrict__ params, unsigned* __restrict__ hist,
    float* __restrict__ out){
  __shared__ unsigned hc[KBINS];
  __shared__ unsigned hg[KBINS];
  __shared__ float ssl;
  const int tid = threadIdx.x;
  for (int i = tid; i < KBINS; i += 256){ hc[i] = 0u; hg[i] = 0u; }
  if (tid == 0) ssl = 0.f;
  __syncthreads();
  const int inst = blockIdx.x;
  const int img  = blockIdx.z;
  const float* pp = params + (img*NINST + inst)*4;
  const float cx = pp[0], cy = pp[1], l11 = pp[2];
  const bool isObj = inst < NOBJ;
  const int idm = isObj ? inst + 1 : inst - NOBJ + 1;
  const int* imap = isObj ? obj_inst : parts_inst;
  const float* predb = pred + (size_t)img*8*NPIX;
  const int sch = isObj ? 6 : 7;
  float sl = 0.f;
  const int base = blockIdx.y*32768;
  for (int it = 0; it < 128; ++it){
    const int pix = base + it*256 + tid;
    const float xm = xym[pix], ym = xym[NPIX + pix];
    float e0 = xm + tanhf(predb[3*NPIX + pix]);
    float e1 = ym + tanhf(predb[4*NPIX + pix]);
    if (isObj){
      e0 += tanhf(predb[0*NPIX + pix]);
      e1 += tanhf(predb[1*NPIX + pix]);
    }
    const float dx = e0 - cx, dy = e1 - cy;
    const float p = expf(-0.5f*l11*(dx*dx + dy*dy));
    const bool lab = (imap[img*NPIX + pix] == idm);
    const float e = lab ? 2.0f*(1.0f - p) : 2.0f*p;
    int b = (int)(e * (KBINS*0.5f));
    b = b < 0 ? 0 : (b > KBINS-1 ? KBINS-1 : b);
    atomicAdd(&hc[b], 1u);
    if (lab){
      atomicAdd(&hg[b], 1u);
      const float s = sigmoidf_(predb[sch*NPIX + pix]);
      const float d = s - p;
      sl += d*d;
    }
  }
  for (int off = 32; off > 0; off >>= 1) sl += __shfl_down(sl, off);
  if ((tid & 63) == 0) atomicAdd(&ssl, sl);
  __syncthreads();
  unsigned* gh = hist + (size_t)(img*NINST + inst)*2*KBINS;
  for (int i = tid; i < KBINS; i += 256){
    const unsigned c = hc[i]; if (c) atomicAdd(&gh[i], c);
    const unsigned g = hg[i]; if (g) atomicAdd(&gh[KBINS + i], g);
  }
  if (tid == 0) atomicAdd(out, ssl * (1.0f/((float)NPIX*BATCH)));
}

// Stage D: Lovász hinge from histogram. Grouped-ties formulation:
// loss = sum over nonempty bins (descending e) of e_bin * (jac_after - jac_before),
// jac(C,G) = 1 - (gts-G)/(gts + C - G); jac(0,0)=0 naturally.
// grid (BATCH*NINST), block 64 (one wave).
__global__ void k_lovasz(const unsigned* __restrict__ hist, const float* __restrict__ params,
                         float* __restrict__ out){
  const int blk = blockIdx.x;
  const int img = blk / NINST, inst = blk % NINST;
  const float gts = params[(img*NINST + inst)*4 + 3];
  if (gts < 0.5f) return;
  const unsigned* hc = hist + (size_t)(img*NINST + inst)*2*KBINS;
  const unsigned* hg = hc + KBINS;
  const int lane = threadIdx.x;
  float Crun = 0.f, Grun = 0.f, loss = 0.f;
  for (int chunk = 0; chunk < KBINS/64; ++chunk){
    const int bin = KBINS - 1 - (chunk*64 + lane);
    const float c = (float)hc[bin];
    const float g = (float)hg[bin];
    float ic = c, ig = g;
    for (int off = 1; off < 64; off <<= 1){
      const float tc = __shfl_up(ic, off); if (lane >= off) ic += tc;
      const float tg = __shfl_up(ig, off); if (lane >= off) ig += tg;
    }
    const float C1 = Crun + ic, G1 = Grun + ig;
    const float C0 = C1 - c,   G0 = G1 - g;
    if (c > 0.f){
      const float e = (bin + 0.5f)*(2.0f/KBINS);
      const float jb = 1.f - (gts - G0)/(gts + C0 - G0);
      const float ja = 1.f - (gts - G1)/(gts + C1 - G1);
      loss += e*(ja - jb);
    }
    Crun += __shfl(ic, 63);
    Grun += __shfl(ig, 63);
  }
  for (int off = 32; off > 0; off >>= 1) loss += __shfl_down(loss, off);
  if (lane == 0){
    const float wN = (inst < NOBJ) ? (float)NOBJ : (float)NPART;
    atomicAdd(out, loss * (1.0f/(wN*BATCH)));
  }
}

extern "C" void kernel_launch(void* const* d_in, const int* in_sizes, int n_in,
                              void* d_out, int out_size, void* d_ws, size_t ws_size,
                              hipStream_t stream){
  (void)in_sizes; (void)n_in; (void)out_size; (void)ws_size;
  const float* pred       = (const float*)d_in[0];
  const int*   obj_inst   = (const int*)d_in[1];
  const int*   obj_lab    = (const int*)d_in[2];
  const int*   parts_inst = (const int*)d_in[3];
  const int*   parts_lab  = (const int*)d_in[4];
  const float* xym        = (const float*)d_in[6];
  float* out = (float*)d_out;
  unsigned* ws = (unsigned*)d_ws;
  unsigned* hist = ws;
  float* accum  = (float*)(ws + ACCUM_OFF);
  float* params = (float*)(ws + PARAMS_OFF);

  hipLaunchKernelGGL(k_zero, dim3(1024), dim3(256), 0, stream, ws, out);
  hipLaunchKernelGGL(k_reduce, dim3(NPIX/4096, BATCH), dim3(256), 0, stream,
                     pred, obj_inst, obj_lab, parts_inst, parts_lab, xym, accum, out);
  hipLaunchKernelGGL(k_params, dim3(1), dim3(128), 0, stream, accum, params, out);
  hipLaunchKernelGGL(k_hist, dim3(NINST, NPIX/32768, BATCH), dim3(256), 0, stream,
                     pred, obj_inst, parts_inst, xym, params, hist, out);
  hipLaunchKernelGGL(k_lovasz, dim3(BATCH*NINST), dim3(64), 0, stream, hist, params, out);
}

// Round 3
// 214.293 us; speedup vs baseline: 1.9725x; 1.9725x over previous
//
#include <hip/hip_runtime.h>

#define BATCH 4
#define NPIX (512*512)
#define NOBJ 8
#define NPART 16
#define NINST 24
#define KB 512
#define L2E 1.44269504f

__device__ __forceinline__ float fexp2(float x){ return __builtin_amdgcn_exp2f(x); }
__device__ __forceinline__ float frcp(float x){ return __builtin_amdgcn_rcpf(x); }
__device__ __forceinline__ float ftanh(float x){ return 1.f - 2.f*frcp(fexp2(2.f*L2E*x) + 1.f); }
__device__ __forceinline__ float fsig(float x){ return frcp(1.f + fexp2(-L2E*x)); }

// ws layout (u32 words): [0, PART) partial hists [B][24][Cn][KB] packed (cnt|fg<<16)
//                        [PART, +480) accum f32 [B][24][5]; then params f32 [B][24][4]

__global__ void k_zero(float* __restrict__ acc, float* __restrict__ out){
  const int i = threadIdx.x;
  if (i < BATCH*NINST*5) acc[i] = 0.f;
  if (i == 0) out[0] = 0.f;
}

// grid (NPIX/1024, BATCH), 256 threads, 4 px/thread via vec4 loads.
__global__ __launch_bounds__(256) void k_reduce(
    const float* __restrict__ pred, const int* __restrict__ obj_inst,
    const int* __restrict__ obj_lab, const int* __restrict__ parts_inst,
    const int* __restrict__ parts_lab, const float* __restrict__ xym,
    float* __restrict__ accum, float* __restrict__ out){
  __shared__ float acc[NINST*5];
  __shared__ float sbg;
  const int tid = threadIdx.x;
  if (tid < NINST*5) acc[tid] = 0.f;
  if (tid == 0) sbg = 0.f;
  __syncthreads();
  const int img = blockIdx.y;
  const float* predb = pred + (size_t)img*8*NPIX;
  const int v = (blockIdx.x*1024 + tid*4) >> 2;
  const int4   o4  = ((const int4*)(obj_inst   + (size_t)img*NPIX))[v];
  const int4   p4  = ((const int4*)(parts_inst + (size_t)img*NPIX))[v];
  const int4   lo4 = ((const int4*)(obj_lab    + (size_t)img*NPIX))[v];
  const int4   lp4 = ((const int4*)(parts_lab  + (size_t)img*NPIX))[v];
  const float4 so4 = ((const float4*)(predb + 2*NPIX))[v];
  const float4 sp4 = ((const float4*)(predb + 5*NPIX))[v];
  const float4 do4 = ((const float4*)(predb + 6*NPIX))[v];
  const float4 dp4 = ((const float4*)(predb + 7*NPIX))[v];
  const float4 xm4 = ((const float4*)xym)[v];
  const float4 ym4 = ((const float4*)(xym + NPIX))[v];
  const int   oid[4] = {o4.x, o4.y, o4.z, o4.w};
  const int   pid[4] = {p4.x, p4.y, p4.z, p4.w};
  const int   lo[4]  = {lo4.x, lo4.y, lo4.z, lo4.w};
  const int   lp[4]  = {lp4.x, lp4.y, lp4.z, lp4.w};
  const float so[4]  = {so4.x, so4.y, so4.z, so4.w};
  const float sp[4]  = {sp4.x, sp4.y, sp4.z, sp4.w};
  const float dob[4] = {do4.x, do4.y, do4.z, do4.w};
  const float dpb[4] = {dp4.x, dp4.y, dp4.z, dp4.w};
  const float xm[4]  = {xm4.x, xm4.y, xm4.z, xm4.w};
  const float ym[4]  = {ym4.x, ym4.y, ym4.z, ym4.w};

  float c0=0,c1=0,c2=0,c3=0,c4=0; int cur=-1;
#define FLUSH_ACC() if (cur>=0){ float* a=&acc[cur*5]; atomicAdd(a,c0); atomicAdd(a+1,c1); \
    atomicAdd(a+2,c2); atomicAdd(a+3,c3); atomicAdd(a+4,c4); }
  #pragma unroll
  for (int j=0;j<4;++j){
    const int id = oid[j];
    if (id>=1 && id<=NOBJ){
      const int slot = id-1;
      if (slot != cur){ FLUSH_ACC(); cur=slot; c0=c1=c2=c3=c4=0.f; }
      c0 += 1.f; c1 += xm[j]; c2 += ym[j]; const float s=so[j]; c3 += s; c4 += s*s;
    }
  }
  FLUSH_ACC();
  c0=c1=c2=c3=c4=0.f; cur=-1;
  #pragma unroll
  for (int j=0;j<4;++j){
    const int id = pid[j];
    if (id>=1 && id<=NPART){
      const int slot = NOBJ + id-1;
      if (slot != cur){ FLUSH_ACC(); cur=slot; c0=c1=c2=c3=c4=0.f; }
      c0 += 1.f; c1 += xm[j]; c2 += ym[j]; const float s=sp[j]; c3 += s; c4 += s*s;
    }
  }
  FLUSH_ACC();
#undef FLUSH_ACC
  float bg = 0.f;
  #pragma unroll
  for (int j=0;j<4;++j){
    if (lo[j] != 1){ const float s = fsig(dob[j]); bg += s*s; }
    if (lp[j] != 1){ const float s = fsig(dpb[j]); bg += s*s; }
  }
  for (int off=32; off>0; off>>=1) bg += __shfl_down(bg, off);
  if ((tid & 63)==0) atomicAdd(&sbg, bg);
  __syncthreads();
  if (tid < NINST*5 && acc[tid] != 0.f) atomicAdd(&accum[img*NINST*5 + tid], acc[tid]);
  if (tid == 0) atomicAdd(out, sbg * (1.0f/((float)NPIX*BATCH)));
}

// 1 block, 128 threads: params + variance term.
__global__ void k_params(const float* __restrict__ accum, float* __restrict__ params,
                         float* __restrict__ out){
  const int t = threadIdx.x;
  if (t >= BATCH*NINST) return;
  const float* a = accum + t*5;
  const float cnt = a[0];
  float cx=0.f, cy=0.f, l11=1.f, var=0.f;
  if (cnt > 0.5f){
    const float inv = 1.0f/cnt;
    cx = a[1]*inv; cy = a[2]*inv;
    const float s = a[3]*inv;
    var = a[4]*inv - s*s;
    if (var < 0.f) var = 0.f;
    l11 = expf(5.5f * s);
  }
  float* p = params + t*4;
  p[0]=cx; p[1]=cy; p[2]=l11; p[3]=cnt;
  const int inst = t % NINST;
  const float wN = (inst < NOBJ) ? 8.f : 16.f;
  if (cnt > 0.5f) atomicAdd(out, var * (10.0f/(wN*BATCH)));
}

// Fused hist: grid (Cn, 3 groups, B), 512 threads. grp0: obj 0-7; grp1: parts 0-7; grp2: parts 8-15.
__global__ __launch_bounds__(512) void k_main(
    const float* __restrict__ pred, const int* __restrict__ obj_inst,
    const int* __restrict__ parts_inst, const float* __restrict__ xym,
    const float* __restrict__ params, unsigned* __restrict__ part,
    float* __restrict__ out, int Cn){
  __shared__ unsigned h[8*KB];
  __shared__ float ssl;
  const int tid = threadIdx.x;
  for (int i = tid; i < 8*KB; i += 512) h[i] = 0u;
  if (tid == 0) ssl = 0.f;
  __syncthreads();
  const int chunk = blockIdx.x, grp = blockIdx.y, img = blockIdx.z;
  const int chunkpix = NPIX / Cn;
  const int base = chunk * chunkpix;
  const float* predb = pred + (size_t)img*8*NPIX;
  const int* imap = ((grp==0) ? obj_inst : parts_inst) + (size_t)img*NPIX;
  const int inst0  = (grp==0) ? 0 : ((grp==1) ? 8 : 16);
  const int idbase = (grp==2) ? 9 : 1;
  const int seedch = (grp==0) ? 6 : 7;
  const float* pp = params + (img*NINST + inst0)*4;
  float cx[8], cy[8], aa[8];
  #pragma unroll
  for (int i=0;i<8;++i){ cx[i]=pp[i*4]; cy[i]=pp[i*4+1]; aa[i] = -0.72134752f*pp[i*4+2]; }
  float sl = 0.f;
  const int iters = chunkpix >> 9;
  for (int it=0; it<iters; ++it){
    const int pix = base + (it<<9) + tid;
    const float xm = xym[pix], ym = xym[NPIX+pix];
    float e0 = xm + ftanh(predb[3*NPIX+pix]);
    float e1 = ym + ftanh(predb[4*NPIX+pix]);
    if (grp==0){ e0 += ftanh(predb[0*NPIX+pix]); e1 += ftanh(predb[1*NPIX+pix]); }
    const int li = imap[pix] - idbase;       // 0..7 when fg in this group
    float pown = 0.f;
    #pragma unroll
    for (int i=0;i<8;++i){
      const float dx = e0-cx[i], dy = e1-cy[i];
      const float p = fexp2(aa[i]*(dx*dx + dy*dy));
      int ib = (int)(p * (float)KB);
      if (ib > KB-1) ib = KB-1;
      const bool lab = (li == i);
      const int bin = lab ? (KB-1-ib) : ib;   // e_fg=2(1-p), e_bg=2p
      if (lab) pown = p;
      atomicAdd(&h[i*KB + bin], lab ? 0x10001u : 1u);
    }
    if (li >= 0 && li < 8){
      const float s = fsig(predb[seedch*NPIX + pix]);
      const float d = s - pown;
      sl += d*d;
    }
  }
  for (int off=32; off>0; off>>=1) sl += __shfl_down(sl, off);
  if ((tid & 63)==0) atomicAdd(&ssl, sl);
  __syncthreads();
  // store partials: [(img*NINST+inst0+i)][Cn=chunk][KB] — plain coalesced stores
  unsigned* dst = part + ((size_t)(img*NINST + inst0)*Cn + chunk)*KB;
  for (int i = tid; i < 8*KB; i += 512){
    const int hi = i >> 9;            // KB==512 == blockDim
    const int bin = i & (KB-1);
    dst[(size_t)hi*Cn*KB + bin] = h[i];
  }
  if (tid == 0) atomicAdd(out, ssl * (1.0f/((float)NPIX*BATCH)));
}

// Lovász from partial hists. grid (B*NINST), 64 threads (1 wave).
__global__ void k_lovasz(const unsigned* __restrict__ part, const float* __restrict__ params,
                         float* __restrict__ out, int Cn){
  const int blk = blockIdx.x;
  const int img = blk / NINST, inst = blk % NINST;
  const float gts = params[(img*NINST + inst)*4 + 3];
  if (gts < 0.5f) return;
  const unsigned* pb = part + (size_t)(img*NINST + inst)*Cn*KB;
  const int lane = threadIdx.x;
  float Crun=0.f, Grun=0.f, loss=0.f;
  for (int ch=0; ch<KB/64; ++ch){
    const int bin = KB-1 - (ch*64 + lane);
    unsigned cnt=0u, fg=0u;
    for (int c=0; c<Cn; ++c){ const unsigned w = pb[c*KB + bin]; cnt += w & 0xFFFFu; fg += w >> 16; }
    const float cc = (float)cnt, g = (float)fg;
    float ic = cc, ig = g;
    for (int off=1; off<64; off<<=1){
      const float tc = __shfl_up(ic, off); if (lane>=off) ic += tc;
      const float tg = __shfl_up(ig, off); if (lane>=off) ig += tg;
    }
    const float C1 = Crun+ic, G1 = Grun+ig, C0 = C1-cc, G0 = G1-g;
    if (cnt){
      const float e = (bin + 0.5f)*(2.0f/KB);
      const float jb = 1.f - (gts-G0)/(gts + C0 - G0);
      const float ja = 1.f - (gts-G1)/(gts + C1 - G1);
      loss += e*(ja - jb);
    }
    Crun += __shfl(ic, 63);
    Grun += __shfl(ig, 63);
  }
  for (int off=32; off>0; off>>=1) loss += __shfl_down(loss, off);
  if (lane == 0){
    const float wN = (inst < NOBJ) ? 8.f : 16.f;
    atomicAdd(out, loss * (1.0f/(wN*BATCH)));
  }
}

extern "C" void kernel_launch(void* const* d_in, const int* in_sizes, int n_in,
                              void* d_out, int out_size, void* d_ws, size_t ws_size,
                              hipStream_t stream){
  (void)in_sizes; (void)n_in; (void)out_size;
  const float* pred       = (const float*)d_in[0];
  const int*   obj_inst   = (const int*)d_in[1];
  const int*   obj_lab    = (const int*)d_in[2];
  const int*   parts_inst = (const int*)d_in[3];
  const int*   parts_lab  = (const int*)d_in[4];
  const float* xym        = (const float*)d_in[6];
  float* out = (float*)d_out;

  const size_t need64 = (size_t)BATCH*NINST*64*KB*4 + 8192;
  const int Cn = (ws_size >= need64) ? 64 : 16;
  unsigned* part = (unsigned*)d_ws;
  const size_t partWords = (size_t)BATCH*NINST*Cn*KB;
  float* accum  = (float*)((unsigned*)d_ws + partWords);
  float* params = accum + BATCH*NINST*5;

  hipLaunchKernelGGL(k_zero, dim3(1), dim3(512), 0, stream, accum, out);
  hipLaunchKernelGGL(k_reduce, dim3(NPIX/1024, BATCH), dim3(256), 0, stream,
                     pred, obj_inst, obj_lab, parts_inst, parts_lab, xym, accum, out);
  hipLaunchKernelGGL(k_params, dim3(1), dim3(128), 0, stream, accum, params, out);
  hipLaunchKernelGGL(k_main, dim3(Cn, 3, BATCH), dim3(512), 0, stream,
                     pred, obj_inst, parts_inst, xym, params, part, out, Cn);
  hipLaunchKernelGGL(k_lovasz, dim3(BATCH*NINST), dim3(64), 0, stream, part, params, out, Cn);
}

// Round 5
// 144.034 us; speedup vs baseline: 2.9346x; 1.4878x over previous
//
#include <hip/hip_runtime.h>

#define BATCH 4
#define NPIX (512*512)
#define NOBJ 8
#define NPART 16
#define NINST 24
#define KB 512
#define L2E 1.44269504f
#define INV511 (1.0f/511.0f)

__device__ __forceinline__ float fexp2(float x){ return __builtin_amdgcn_exp2f(x); }
__device__ __forceinline__ float frcp(float x){ return __builtin_amdgcn_rcpf(x); }
__device__ __forceinline__ float ftanh(float x){ return 1.f - 2.f*frcp(fexp2(2.f*L2E*x) + 1.f); }
__device__ __forceinline__ float fsig(float x){ return frcp(1.f + fexp2(-L2E*x)); }

// ws: [0, B*24*Cn*KB) u32 partial hists packed (cnt | fg<<16), layout [instG][Cn][KB]
//     then accum f32 [B][24][5], params f32 [B][24][4]

__global__ void k_zero(float* __restrict__ acc, float* __restrict__ out){
  const int i = threadIdx.x;
  if (i < BATCH*NINST*5) acc[i] = 0.f;
  if (i == 0) out[0] = 0.f;
}

// grid (NPIX/1024, BATCH), 256 thr, 4 px/thread vec4. Only inst maps + sigma channels.
__global__ __launch_bounds__(256) void k_reduce(
    const float* __restrict__ pred, const int* __restrict__ obj_inst,
    const int* __restrict__ parts_inst, float* __restrict__ accum){
  __shared__ float acc[NINST*5];
  const int tid = threadIdx.x;
  if (tid < NINST*5) acc[tid] = 0.f;
  __syncthreads();
  const int img = blockIdx.y;
  const float* predb = pred + (size_t)img*8*NPIX;
  const int pix0 = blockIdx.x*1024 + tid*4;
  const int v = pix0 >> 2;
  const int4   o4  = ((const int4*)(obj_inst   + (size_t)img*NPIX))[v];
  const int4   p4  = ((const int4*)(parts_inst + (size_t)img*NPIX))[v];
  const float4 so4 = ((const float4*)(predb + 2*NPIX))[v];
  const float4 sp4 = ((const float4*)(predb + 5*NPIX))[v];
  const int   oid[4] = {o4.x, o4.y, o4.z, o4.w};
  const int   pid[4] = {p4.x, p4.y, p4.z, p4.w};
  const float so[4]  = {so4.x, so4.y, so4.z, so4.w};
  const float sp[4]  = {sp4.x, sp4.y, sp4.z, sp4.w};
  float c0=0,c1=0,c2=0,c3=0,c4=0; int cur=-1;
#define FLUSH_ACC() if (cur>=0){ float* a=&acc[cur*5]; atomicAdd(a,c0); atomicAdd(a+1,c1); \
    atomicAdd(a+2,c2); atomicAdd(a+3,c3); atomicAdd(a+4,c4); }
  #pragma unroll
  for (int j=0;j<4;++j){
    const int id = oid[j];
    if (id>=1 && id<=NOBJ){
      const int slot = id-1;
      if (slot != cur){ FLUSH_ACC(); cur=slot; c0=c1=c2=c3=c4=0.f; }
      const int pix = pix0+j;
      c0 += 1.f; c1 += (float)(pix & 511)*INV511; c2 += (float)(pix >> 9)*INV511;
      const float s=so[j]; c3 += s; c4 += s*s;
    }
  }
  FLUSH_ACC();
  c0=c1=c2=c3=c4=0.f; cur=-1;
  #pragma unroll
  for (int j=0;j<4;++j){
    const int id = pid[j];
    if (id>=1 && id<=NPART){
      const int slot = NOBJ + id-1;
      if (slot != cur){ FLUSH_ACC(); cur=slot; c0=c1=c2=c3=c4=0.f; }
      const int pix = pix0+j;
      c0 += 1.f; c1 += (float)(pix & 511)*INV511; c2 += (float)(pix >> 9)*INV511;
      const float s=sp[j]; c3 += s; c4 += s*s;
    }
  }
  FLUSH_ACC();
#undef FLUSH_ACC
  __syncthreads();
  if (tid < NINST*5 && acc[tid] != 0.f) atomicAdd(&accum[img*NINST*5 + tid], acc[tid]);
}

__global__ void k_params(const float* __restrict__ accum, float* __restrict__ params,
                         float* __restrict__ out){
  const int t = threadIdx.x;
  if (t >= BATCH*NINST) return;
  const float* a = accum + t*5;
  const float cnt = a[0];
  float cx=0.f, cy=0.f, l11=1.f, var=0.f;
  if (cnt > 0.5f){
    const float inv = 1.0f/cnt;
    cx = a[1]*inv; cy = a[2]*inv;
    const float s = a[3]*inv;
    var = a[4]*inv - s*s;
    if (var < 0.f) var = 0.f;
    l11 = expf(5.5f * s);
  }
  float* p = params + t*4;
  p[0]=cx; p[1]=cy; p[2]=l11; p[3]=cnt;
  const int inst = t % NINST;
  const float wN = (inst < NOBJ) ? 8.f : 16.f;
  if (cnt > 0.5f) atomicAdd(out, var * (10.0f/(wN*BATCH)));
}

// grid (Cn, 3, B), 512 thr, 4 px/thread. grp0: obj 0-7 (+obj bg seed);
// grp1: parts 1-8 (+parts bg seed); grp2: parts 9-16.
__global__ __launch_bounds__(512) void k_main(
    const float* __restrict__ pred, const int* __restrict__ obj_inst,
    const int* __restrict__ parts_inst, const float* __restrict__ params,
    unsigned* __restrict__ part, float* __restrict__ out, int Cn){
  __shared__ unsigned h[8*KB];
  __shared__ float ssl;
  const int tid = threadIdx.x;
  for (int i = tid; i < 8*KB; i += 512) h[i] = 0u;
  if (tid == 0) ssl = 0.f;
  __syncthreads();
  const int chunk = blockIdx.x, grp = blockIdx.y, img = blockIdx.z;
  const int chunkpix = NPIX / Cn;
  const int base = chunk * chunkpix;
  const float* predb = pred + (size_t)img*8*NPIX;
  const int* imap = ((grp==0) ? obj_inst : parts_inst) + (size_t)img*NPIX;
  const int inst0  = (grp==0) ? 0 : ((grp==1) ? 8 : 16);
  const int idbase = (grp==2) ? 9 : 1;
  const int seedch = (grp==0) ? 6 : 7;
  const float* pp = params + (img*NINST + inst0)*4;
  float cx[8], cy[8], aa[8];
  #pragma unroll
  for (int i=0;i<8;++i){ cx[i]=pp[i*4]; cy[i]=pp[i*4+1]; aa[i] = -0.72134752f*pp[i*4+2]; }
  float sl = 0.f;
  const int iters = chunkpix >> 11;
  for (int it=0; it<iters; ++it){
    const int pix0 = base + (it<<11) + tid*4;
    const int v = pix0 >> 2;
    const float4 t3 = ((const float4*)(predb + 3*NPIX))[v];
    const float4 t4 = ((const float4*)(predb + 4*NPIX))[v];
    const float4 sd = ((const float4*)(predb + (size_t)seedch*NPIX))[v];
    const int4   im4 = ((const int4*)imap)[v];
    float4 t0, t1;
    if (grp==0){ t0 = ((const float4*)(predb))[v]; t1 = ((const float4*)(predb + NPIX))[v]; }
    const float a3[4] = {t3.x,t3.y,t3.z,t3.w};
    const float a4[4] = {t4.x,t4.y,t4.z,t4.w};
    const float sdv[4]= {sd.x,sd.y,sd.z,sd.w};
    const float a0[4] = {t0.x,t0.y,t0.z,t0.w};
    const float a1[4] = {t1.x,t1.y,t1.z,t1.w};
    const int   im[4] = {im4.x,im4.y,im4.z,im4.w};
    #pragma unroll
    for (int j=0;j<4;++j){
      const int pix = pix0 + j;
      const float xm = (float)(pix & 511)*INV511;
      const float ym = (float)(pix >> 9)*INV511;
      float e0 = xm + ftanh(a3[j]);
      float e1 = ym + ftanh(a4[j]);
      if (grp==0){ e0 += ftanh(a0[j]); e1 += ftanh(a1[j]); }
      const int li = im[j] - idbase;
      const float s = fsig(sdv[j]);
      float pown = 0.f;
      #pragma unroll
      for (int i=0;i<8;++i){
        const float dx = e0-cx[i], dy = e1-cy[i];
        const float p = fexp2(aa[i]*(dx*dx + dy*dy));
        int ib = (int)(p * (float)KB);
        if (ib > KB-1) ib = KB-1;
        const bool lab = (li == i);
        const int bin = lab ? (KB-1-ib) : ib;
        if (lab) pown = p;
        atomicAdd(&h[i*KB + bin], lab ? 0x10001u : 1u);
      }
      const bool fg = (li >= 0 && li < 8);
      if (fg){ const float d = s - pown; sl += d*d; }
      else if (grp==0 || (grp==1 && li==-1)) sl += s*s;   // bg seed (label!=1 <=> inst==0)
    }
  }
  for (int off=32; off>0; off>>=1) sl += __shfl_down(sl, off);
  if ((tid & 63)==0) atomicAdd(&ssl, sl);
  __syncthreads();
  unsigned* dst = part + ((size_t)(img*NINST + inst0)*Cn + chunk)*KB;
  for (int i = tid; i < 8*KB; i += 512){
    const int hi = i >> 9;
    const int bin = i & (KB-1);
    dst[(size_t)hi*Cn*KB + bin] = h[i];
  }
  if (tid == 0) atomicAdd(out, ssl * (1.0f/((float)NPIX*BATCH)));
}

// grid (B*NINST), 512 thr: thread t owns bin t; coalesced Cn-sum, block scan, loss.
__global__ __launch_bounds__(512) void k_lovasz(
    const unsigned* __restrict__ part, const float* __restrict__ params,
    float* __restrict__ out, int Cn){
  __shared__ float sc[KB], sg[KB];
  __shared__ float wt[16];
  __shared__ float lsum[8];
  const int blk = blockIdx.x;            // == img*NINST + inst
  const int inst = blk % NINST;
  const float gts = params[blk*4 + 3];
  if (gts < 0.5f) return;                // uniform exit
  const int t = threadIdx.x;
  const unsigned* pb = part + (size_t)blk*Cn*KB;
  unsigned cnt=0u, fg=0u;
  for (int c=0;c<Cn;++c){ const unsigned w = pb[(size_t)c*KB + t]; cnt += w & 0xFFFFu; fg += w >> 16; }
  sc[KB-1-t] = (float)cnt; sg[KB-1-t] = (float)fg;   // descending-error order
  __syncthreads();
  const float c = sc[t], g = sg[t];
  float ic = c, ig = g;
  for (int off=1; off<64; off<<=1){
    const float tc = __shfl_up(ic, off); const float tg = __shfl_up(ig, off);
    if ((t & 63) >= off){ ic += tc; ig += tg; }
  }
  const int wid = t >> 6, lane = t & 63;
  if (lane == 63){ wt[wid] = ic; wt[8+wid] = ig; }
  __syncthreads();
  float offc = 0.f, offg = 0.f;
  for (int w2=0; w2<wid; ++w2){ offc += wt[w2]; offg += wt[8+w2]; }
  const float C1 = offc + ic, G1 = offg + ig, C0 = C1 - c, G0 = G1 - g;
  float l = 0.f;
  if (c > 0.f){
    const int bin = KB-1-t;
    const float e = (bin + 0.5f)*(2.0f/KB);
    const float jb = 1.f - (gts-G0)/(gts + C0 - G0);
    const float ja = 1.f - (gts-G1)/(gts + C1 - G1);
    l = e*(ja - jb);
  }
  for (int off=32; off>0; off>>=1) l += __shfl_down(l, off);
  if (lane == 0) lsum[wid] = l;
  __syncthreads();
  if (t == 0){
    float tot = 0.f;
    #pragma unroll
    for (int w2=0; w2<8; ++w2) tot += lsum[w2];
    const float wN = (inst < NOBJ) ? 8.f : 16.f;
    atomicAdd(out, tot * (1.0f/(wN*BATCH)));
  }
}

extern "C" void kernel_launch(void* const* d_in, const int* in_sizes, int n_in,
                              void* d_out, int out_size, void* d_ws, size_t ws_size,
                              hipStream_t stream){
  (void)in_sizes; (void)n_in; (void)out_size;
  const float* pred       = (const float*)d_in[0];
  const int*   obj_inst   = (const int*)d_in[1];
  const int*   parts_inst = (const int*)d_in[3];
  const float* xym        = (const float*)d_in[6]; (void)xym;
  float* out = (float*)d_out;

  const size_t need64 = (size_t)BATCH*NINST*64*KB*4 + 8192;
  const int Cn = (ws_size >= need64) ? 64 : 16;
  unsigned* part = (unsigned*)d_ws;
  const size_t partWords = (size_t)BATCH*NINST*Cn*KB;
  float* accum  = (float*)((unsigned*)d_ws + partWords);
  float* params = accum + BATCH*NINST*5;

  hipLaunchKernelGGL(k_zero, dim3(1), dim3(512), 0, stream, accum, out);
  hipLaunchKernelGGL(k_reduce, dim3(NPIX/1024, BATCH), dim3(256), 0, stream,
                     pred, obj_inst, parts_inst, accum);
  hipLaunchKernelGGL(k_params, dim3(1), dim3(128), 0, stream, accum, params, out);
  hipLaunchKernelGGL(k_main, dim3(Cn, 3, BATCH), dim3(512), 0, stream,
                     pred, obj_inst, parts_inst, params, part, out, Cn);
  hipLaunchKernelGGL(k_lovasz, dim3(BATCH*NINST), dim3(512), 0, stream, part, params, out, Cn);
}

// Round 6
// 139.794 us; speedup vs baseline: 3.0237x; 1.0303x over previous
//
#include <hip/hip_runtime.h>

#define BATCH 4
#define NPIX (512*512)
#define NOBJ 8
#define NPART 16
#define NINST 24
#define KB 512
#define L2E 1.44269504f
#define INV511 (1.0f/511.0f)

__device__ __forceinline__ float fexp2(float x){ return __builtin_amdgcn_exp2f(x); }
__device__ __forceinline__ float frcp(float x){ return __builtin_amdgcn_rcpf(x); }
__device__ __forceinline__ float ftanh(float x){ return 1.f - 2.f*frcp(fexp2(2.f*L2E*x) + 1.f); }
__device__ __forceinline__ float fsig(float x){ return frcp(1.f + fexp2(-L2E*x)); }

// ws: [0, B*24*Cn*KB) u32 partial hists packed (cnt | fg<<16), layout [instG][Cn][KB]
//     then accum f32 [B][24][5] (cnt, sx, sy, ssig, ssig2)

__global__ void k_zero(float* __restrict__ acc, float* __restrict__ out){
  const int i = threadIdx.x;
  if (i < BATCH*NINST*5) acc[i] = 0.f;
  if (i == 0) out[0] = 0.f;
}

// grid (NPIX/1024, BATCH), 256 thr, 4 px/thread vec4.
__global__ __launch_bounds__(256) void k_reduce(
    const float* __restrict__ pred, const int* __restrict__ obj_inst,
    const int* __restrict__ parts_inst, float* __restrict__ accum){
  __shared__ float acc[NINST*5];
  const int tid = threadIdx.x;
  if (tid < NINST*5) acc[tid] = 0.f;
  __syncthreads();
  const int img = blockIdx.y;
  const float* predb = pred + (size_t)img*8*NPIX;
  const int pix0 = blockIdx.x*1024 + tid*4;
  const int v = pix0 >> 2;
  const int4   o4  = ((const int4*)(obj_inst   + (size_t)img*NPIX))[v];
  const int4   p4  = ((const int4*)(parts_inst + (size_t)img*NPIX))[v];
  const float4 so4 = ((const float4*)(predb + 2*NPIX))[v];
  const float4 sp4 = ((const float4*)(predb + 5*NPIX))[v];
  const int   oid[4] = {o4.x, o4.y, o4.z, o4.w};
  const int   pid[4] = {p4.x, p4.y, p4.z, p4.w};
  const float so[4]  = {so4.x, so4.y, so4.z, so4.w};
  const float sp[4]  = {sp4.x, sp4.y, sp4.z, sp4.w};
  float c0=0,c1=0,c2=0,c3=0,c4=0; int cur=-1;
#define FLUSH_ACC() if (cur>=0){ float* a=&acc[cur*5]; atomicAdd(a,c0); atomicAdd(a+1,c1); \
    atomicAdd(a+2,c2); atomicAdd(a+3,c3); atomicAdd(a+4,c4); }
  #pragma unroll
  for (int j=0;j<4;++j){
    const int id = oid[j];
    if (id>=1 && id<=NOBJ){
      const int slot = id-1;
      if (slot != cur){ FLUSH_ACC(); cur=slot; c0=c1=c2=c3=c4=0.f; }
      const int pix = pix0+j;
      c0 += 1.f; c1 += (float)(pix & 511)*INV511; c2 += (float)(pix >> 9)*INV511;
      const float s=so[j]; c3 += s; c4 += s*s;
    }
  }
  FLUSH_ACC();
  c0=c1=c2=c3=c4=0.f; cur=-1;
  #pragma unroll
  for (int j=0;j<4;++j){
    const int id = pid[j];
    if (id>=1 && id<=NPART){
      const int slot = NOBJ + id-1;
      if (slot != cur){ FLUSH_ACC(); cur=slot; c0=c1=c2=c3=c4=0.f; }
      const int pix = pix0+j;
      c0 += 1.f; c1 += (float)(pix & 511)*INV511; c2 += (float)(pix >> 9)*INV511;
      const float s=sp[j]; c3 += s; c4 += s*s;
    }
  }
  FLUSH_ACC();
#undef FLUSH_ACC
  __syncthreads();
  if (tid < NINST*5 && acc[tid] != 0.f) atomicAdd(&accum[img*NINST*5 + tid], acc[tid]);
}

// Fused single-pass: grid (Cn, B), 512 thr, 4 px/thread, all 24 instances.
// Inlines params (from accum), var term (chunk==0), both seed losses.
__global__ __launch_bounds__(512) void k_main(
    const float* __restrict__ pred, const int* __restrict__ obj_inst,
    const int* __restrict__ parts_inst, const float* __restrict__ accum,
    unsigned* __restrict__ part, float* __restrict__ out, int Cn){
  __shared__ unsigned h[NINST*KB];       // 48KB
  __shared__ float pz[NINST*3];          // cx, cy, aa
  __shared__ float ssl;
  const int tid = threadIdx.x;
  for (int i = tid; i < NINST*KB; i += 512) h[i] = 0u;
  if (tid == 0) ssl = 0.f;
  const int chunk = blockIdx.x, img = blockIdx.y;
  if (tid < NINST){
    const float* a = accum + (img*NINST + tid)*5;
    const float cnt = a[0];
    float cx=0.f, cy=0.f, aa=-0.72134752f, var=0.f;
    if (cnt > 0.5f){
      const float inv = 1.0f/cnt;
      cx = a[1]*inv; cy = a[2]*inv;
      const float s = a[3]*inv;
      var = a[4]*inv - s*s; if (var < 0.f) var = 0.f;
      aa = -0.72134752f*expf(5.5f*s);    // -0.5*log2(e)*l11
    }
    pz[tid*3]=cx; pz[tid*3+1]=cy; pz[tid*3+2]=aa;
    if (chunk == 0 && cnt > 0.5f){
      const float wN = (tid < NOBJ) ? 8.f : 16.f;
      atomicAdd(out, var * (10.0f/(wN*BATCH)));
    }
  }
  __syncthreads();
  float cx[NINST], cy[NINST], aa[NINST];
  #pragma unroll
  for (int i=0;i<NINST;++i){ cx[i]=pz[i*3]; cy[i]=pz[i*3+1]; aa[i]=pz[i*3+2]; }
  const float* predb = pred + (size_t)img*8*NPIX;
  const int* omap = obj_inst   + (size_t)img*NPIX;
  const int* pmap = parts_inst + (size_t)img*NPIX;
  float sl = 0.f;
  const int chunkpix = NPIX / Cn;
  const int base = chunk * chunkpix;
  const int iters = chunkpix >> 11;
  for (int it=0; it<iters; ++it){
    const int pix0 = base + (it<<11) + tid*4;
    const int v = pix0 >> 2;
    const float4 t0 = ((const float4*)(predb + 0*NPIX))[v];
    const float4 t1 = ((const float4*)(predb + 1*NPIX))[v];
    const float4 t3 = ((const float4*)(predb + 3*NPIX))[v];
    const float4 t4 = ((const float4*)(predb + 4*NPIX))[v];
    const float4 s6 = ((const float4*)(predb + 6*NPIX))[v];
    const float4 s7 = ((const float4*)(predb + 7*NPIX))[v];
    const int4   om4 = ((const int4*)omap)[v];
    const int4   pm4 = ((const int4*)pmap)[v];
    const float a0[4] = {t0.x,t0.y,t0.z,t0.w};
    const float a1[4] = {t1.x,t1.y,t1.z,t1.w};
    const float a3[4] = {t3.x,t3.y,t3.z,t3.w};
    const float a4[4] = {t4.x,t4.y,t4.z,t4.w};
    const float d6[4] = {s6.x,s6.y,s6.z,s6.w};
    const float d7[4] = {s7.x,s7.y,s7.z,s7.w};
    const int   om[4] = {om4.x,om4.y,om4.z,om4.w};
    const int   pm[4] = {pm4.x,pm4.y,pm4.z,pm4.w};
    #pragma unroll
    for (int j=0;j<4;++j){
      const int pix = pix0 + j;
      const float xm = (float)(pix & 511)*INV511;
      const float ym = (float)(pix >> 9)*INV511;
      const float ep0 = xm + ftanh(a3[j]);       // parts emb
      const float ep1 = ym + ftanh(a4[j]);
      const float eo0 = ep0 + ftanh(a0[j]);      // obj emb
      const float eo1 = ep1 + ftanh(a1[j]);
      const int lio = om[j] - 1;                 // 0..7 when obj fg
      const int lip = pm[j] - 1;                 // 0..15 when parts fg
      const float so = fsig(d6[j]);
      const float sp = fsig(d7[j]);
      float pwo = 0.f, pwp = 0.f;
      #pragma unroll
      for (int i=0;i<NOBJ;++i){
        const float dx = eo0-cx[i], dy = eo1-cy[i];
        const float p = fexp2(aa[i]*(dx*dx + dy*dy));
        int ib = (int)(p * (float)KB); if (ib > KB-1) ib = KB-1;
        const bool lab = (lio == i);
        if (lab) pwo = p;
        atomicAdd(&h[i*KB + (lab ? (KB-1-ib) : ib)], lab ? 0x10001u : 1u);
      }
      #pragma unroll
      for (int i=0;i<NPART;++i){
        const int ii = NOBJ + i;
        const float dx = ep0-cx[ii], dy = ep1-cy[ii];
        const float p = fexp2(aa[ii]*(dx*dx + dy*dy));
        int ib = (int)(p * (float)KB); if (ib > KB-1) ib = KB-1;
        const bool lab = (lip == i);
        if (lab) pwp = p;
        atomicAdd(&h[ii*KB + (lab ? (KB-1-ib) : ib)], lab ? 0x10001u : 1u);
      }
      const float dso = (lio >= 0) ? (so - pwo) : so;   // bg: label!=1 <=> inst==0
      const float dsp = (lip >= 0) ? (sp - pwp) : sp;
      sl += dso*dso + dsp*dsp;
    }
  }
  for (int off=32; off>0; off>>=1) sl += __shfl_down(sl, off);
  if ((tid & 63)==0) atomicAdd(&ssl, sl);
  __syncthreads();
  unsigned* dst = part + ((size_t)img*NINST*Cn + chunk)*KB;
  for (int i = tid; i < NINST*KB; i += 512){
    const int hi = i >> 9;
    const int bin = i & (KB-1);
    dst[(size_t)hi*Cn*KB + bin] = h[i];
  }
  if (tid == 0) atomicAdd(out, ssl * (1.0f/((float)NPIX*BATCH)));
}

// grid (B*NINST), 512 thr: thread t owns bin t; coalesced Cn-sum, block scan, loss.
__global__ __launch_bounds__(512) void k_lovasz(
    const unsigned* __restrict__ part, const float* __restrict__ accum,
    float* __restrict__ out, int Cn){
  __shared__ float sc[KB], sg[KB];
  __shared__ float wt[16];
  __shared__ float lsum[8];
  const int blk = blockIdx.x;            // == img*NINST + inst
  const int inst = blk % NINST;
  const float gts = accum[blk*5];
  if (gts < 0.5f) return;                // block-uniform exit
  const int t = threadIdx.x;
  const unsigned* pb = part + (size_t)blk*Cn*KB;
  unsigned cnt=0u, fg=0u;
  for (int c=0;c<Cn;++c){ const unsigned w = pb[(size_t)c*KB + t]; cnt += w & 0xFFFFu; fg += w >> 16; }
  sc[KB-1-t] = (float)cnt; sg[KB-1-t] = (float)fg;   // descending-error order
  __syncthreads();
  const float c = sc[t], g = sg[t];
  float ic = c, ig = g;
  for (int off=1; off<64; off<<=1){
    const float tc = __shfl_up(ic, off); const float tg = __shfl_up(ig, off);
    if ((t & 63) >= off){ ic += tc; ig += tg; }
  }
  const int wid = t >> 6, lane = t & 63;
  if (lane == 63){ wt[wid] = ic; wt[8+wid] = ig; }
  __syncthreads();
  float offc = 0.f, offg = 0.f;
  for (int w2=0; w2<wid; ++w2){ offc += wt[w2]; offg += wt[8+w2]; }
  const float C1 = offc + ic, G1 = offg + ig, C0 = C1 - c, G0 = G1 - g;
  float l = 0.f;
  if (c > 0.f){
    const int bin = KB-1-t;
    const float e = (bin + 0.5f)*(2.0f/KB);
    const float jb = 1.f - (gts-G0)/(gts + C0 - G0);
    const float ja = 1.f - (gts-G1)/(gts + C1 - G1);
    l = e*(ja - jb);
  }
  for (int off=32; off>0; off>>=1) l += __shfl_down(l, off);
  if (lane == 0) lsum[wid] = l;
  __syncthreads();
  if (t == 0){
    float tot = 0.f;
    #pragma unroll
    for (int w2=0; w2<8; ++w2) tot += lsum[w2];
    const float wN = (inst < NOBJ) ? 8.f : 16.f;
    atomicAdd(out, tot * (1.0f/(wN*BATCH)));
  }
}

extern "C" void kernel_launch(void* const* d_in, const int* in_sizes, int n_in,
                              void* d_out, int out_size, void* d_ws, size_t ws_size,
                              hipStream_t stream){
  (void)in_sizes; (void)n_in; (void)out_size;
  const float* pred       = (const float*)d_in[0];
  const int*   obj_inst   = (const int*)d_in[1];
  const int*   parts_inst = (const int*)d_in[3];
  float* out = (float*)d_out;

  const size_t need64 = (size_t)BATCH*NINST*64*KB*4 + 8192;
  const int Cn = (ws_size >= need64) ? 64 : 16;
  unsigned* part = (unsigned*)d_ws;
  const size_t partWords = (size_t)BATCH*NINST*Cn*KB;
  float* accum  = (float*)((unsigned*)d_ws + partWords);

  hipLaunchKernelGGL(k_zero, dim3(1), dim3(512), 0, stream, accum, out);
  hipLaunchKernelGGL(k_reduce, dim3(NPIX/1024, BATCH), dim3(256), 0, stream,
                     pred, obj_inst, parts_inst, accum);
  hipLaunchKernelGGL(k_main, dim3(Cn, BATCH), dim3(512), 0, stream,
                     pred, obj_inst, parts_inst, accum, part, out, Cn);
  hipLaunchKernelGGL(k_lovasz, dim3(BATCH*NINST), dim3(512), 0, stream, part, accum, out, Cn);
}

// Round 7
// 132.361 us; speedup vs baseline: 3.1935x; 1.0562x over previous
//
#include <hip/hip_runtime.h>

#define BATCH 4
#define NPIX (512*512)
#define NOBJ 8
#define NPART 16
#define NINST 24
#define KB 256
#define L2E 1.44269504f
#define INV511 (1.0f/511.0f)

__device__ __forceinline__ float fexp2(float x){ return __builtin_amdgcn_exp2f(x); }
__device__ __forceinline__ float frcp(float x){ return __builtin_amdgcn_rcpf(x); }
__device__ __forceinline__ float ftanh(float x){ return 1.f - 2.f*frcp(fexp2(2.f*L2E*x) + 1.f); }
__device__ __forceinline__ float fsig(float x){ return frcp(1.f + fexp2(-L2E*x)); }

// ws: [0, B*24*Cn*KB) u32 partial hists packed (cnt | fg<<16), layout [instG][Cn][KB]
//     then accum f32 [B][24][5] (cnt, sx, sy, ssig, ssig2)

__global__ void k_zero(float* __restrict__ acc, float* __restrict__ out){
  const int i = threadIdx.x;
  if (i < BATCH*NINST*5) acc[i] = 0.f;
  if (i == 0) out[0] = 0.f;
}

// grid (NPIX/2048, BATCH), 256 thr, 8 px/thread vec4 (run-combined LDS atomics).
__global__ __launch_bounds__(256) void k_reduce(
    const float* __restrict__ pred, const int* __restrict__ obj_inst,
    const int* __restrict__ parts_inst, float* __restrict__ accum){
  __shared__ float acc[NINST*5];
  const int tid = threadIdx.x;
  if (tid < NINST*5) acc[tid] = 0.f;
  __syncthreads();
  const int img = blockIdx.y;
  const float* predb = pred + (size_t)img*8*NPIX;
  const int pix0 = blockIdx.x*2048 + tid*8;
  const int v = pix0 >> 2;
  const int*   obase = obj_inst   + (size_t)img*NPIX;
  const int*   pbase = parts_inst + (size_t)img*NPIX;
  int   oid[8], pid[8];
  float so[8], sp[8];
  {
    const int4 a = ((const int4*)obase)[v],   b = ((const int4*)obase)[v+1];
    oid[0]=a.x;oid[1]=a.y;oid[2]=a.z;oid[3]=a.w;oid[4]=b.x;oid[5]=b.y;oid[6]=b.z;oid[7]=b.w;
  }
  {
    const int4 a = ((const int4*)pbase)[v],   b = ((const int4*)pbase)[v+1];
    pid[0]=a.x;pid[1]=a.y;pid[2]=a.z;pid[3]=a.w;pid[4]=b.x;pid[5]=b.y;pid[6]=b.z;pid[7]=b.w;
  }
  {
    const float4 a = ((const float4*)(predb+2*NPIX))[v], b = ((const float4*)(predb+2*NPIX))[v+1];
    so[0]=a.x;so[1]=a.y;so[2]=a.z;so[3]=a.w;so[4]=b.x;so[5]=b.y;so[6]=b.z;so[7]=b.w;
  }
  {
    const float4 a = ((const float4*)(predb+5*NPIX))[v], b = ((const float4*)(predb+5*NPIX))[v+1];
    sp[0]=a.x;sp[1]=a.y;sp[2]=a.z;sp[3]=a.w;sp[4]=b.x;sp[5]=b.y;sp[6]=b.z;sp[7]=b.w;
  }
  float c0=0,c1=0,c2=0,c3=0,c4=0; int cur=-1;
#define FLUSH_ACC() if (cur>=0){ float* a=&acc[cur*5]; atomicAdd(a,c0); atomicAdd(a+1,c1); \
    atomicAdd(a+2,c2); atomicAdd(a+3,c3); atomicAdd(a+4,c4); }
  #pragma unroll
  for (int j=0;j<8;++j){
    const int id = oid[j];
    if (id>=1 && id<=NOBJ){
      const int slot = id-1;
      if (slot != cur){ FLUSH_ACC(); cur=slot; c0=c1=c2=c3=c4=0.f; }
      const int pix = pix0+j;
      c0 += 1.f; c1 += (float)(pix & 511)*INV511; c2 += (float)(pix >> 9)*INV511;
      const float s=so[j]; c3 += s; c4 += s*s;
    }
  }
  FLUSH_ACC();
  c0=c1=c2=c3=c4=0.f; cur=-1;
  #pragma unroll
  for (int j=0;j<8;++j){
    const int id = pid[j];
    if (id>=1 && id<=NPART){
      const int slot = NOBJ + id-1;
      if (slot != cur){ FLUSH_ACC(); cur=slot; c0=c1=c2=c3=c4=0.f; }
      const int pix = pix0+j;
      c0 += 1.f; c1 += (float)(pix & 511)*INV511; c2 += (float)(pix >> 9)*INV511;
      const float s=sp[j]; c3 += s; c4 += s*s;
    }
  }
  FLUSH_ACC();
#undef FLUSH_ACC
  __syncthreads();
  if (tid < NINST*5 && acc[tid] != 0.f) atomicAdd(&accum[img*NINST*5 + tid], acc[tid]);
}

// Fused single-pass: grid (Cn, B), 256 thr, 4 px/thread, all 24 instances.
// Inlines params (from accum), var term (chunk==0), both seed losses.
__global__ __launch_bounds__(256) void k_main(
    const float* __restrict__ pred, const int* __restrict__ obj_inst,
    const int* __restrict__ parts_inst, const float* __restrict__ accum,
    unsigned* __restrict__ part, float* __restrict__ out, int Cn){
  __shared__ unsigned h[NINST*KB];       // 24KB
  __shared__ float pz[NINST*3];          // cx, cy, aa
  __shared__ float ssl;
  const int tid = threadIdx.x;
  for (int i = tid; i < NINST*KB; i += 256) h[i] = 0u;
  if (tid == 0) ssl = 0.f;
  const int chunk = blockIdx.x, img = blockIdx.y;
  if (tid < NINST){
    const float* a = accum + (img*NINST + tid)*5;
    const float cnt = a[0];
    float cx=0.f, cy=0.f, aa=-0.72134752f, var=0.f;
    if (cnt > 0.5f){
      const float inv = 1.0f/cnt;
      cx = a[1]*inv; cy = a[2]*inv;
      const float s = a[3]*inv;
      var = a[4]*inv - s*s; if (var < 0.f) var = 0.f;
      aa = -0.72134752f*expf(5.5f*s);    // -0.5*log2(e)*l11
    }
    pz[tid*3]=cx; pz[tid*3+1]=cy; pz[tid*3+2]=aa;
    if (chunk == 0 && cnt > 0.5f){
      const float wN = (tid < NOBJ) ? 8.f : 16.f;
      atomicAdd(out, var * (10.0f/(wN*BATCH)));
    }
  }
  __syncthreads();
  float cx[NINST], cy[NINST], aa[NINST];
  #pragma unroll
  for (int i=0;i<NINST;++i){ cx[i]=pz[i*3]; cy[i]=pz[i*3+1]; aa[i]=pz[i*3+2]; }
  const float* predb = pred + (size_t)img*8*NPIX;
  const int* omap = obj_inst   + (size_t)img*NPIX;
  const int* pmap = parts_inst + (size_t)img*NPIX;
  float sl = 0.f;
  const int chunkpix = NPIX / Cn;
  const int base = chunk * chunkpix;
  const int iters = chunkpix >> 10;      // 256 thr * 4 px
  for (int it=0; it<iters; ++it){
    const int pix0 = base + (it<<10) + tid*4;
    const int v = pix0 >> 2;
    const float4 t0 = ((const float4*)(predb + 0*NPIX))[v];
    const float4 t1 = ((const float4*)(predb + 1*NPIX))[v];
    const float4 t3 = ((const float4*)(predb + 3*NPIX))[v];
    const float4 t4 = ((const float4*)(predb + 4*NPIX))[v];
    const float4 s6 = ((const float4*)(predb + 6*NPIX))[v];
    const float4 s7 = ((const float4*)(predb + 7*NPIX))[v];
    const int4   om4 = ((const int4*)omap)[v];
    const int4   pm4 = ((const int4*)pmap)[v];
    const float a0[4] = {t0.x,t0.y,t0.z,t0.w};
    const float a1[4] = {t1.x,t1.y,t1.z,t1.w};
    const float a3[4] = {t3.x,t3.y,t3.z,t3.w};
    const float a4[4] = {t4.x,t4.y,t4.z,t4.w};
    const float d6[4] = {s6.x,s6.y,s6.z,s6.w};
    const float d7[4] = {s7.x,s7.y,s7.z,s7.w};
    const int   om[4] = {om4.x,om4.y,om4.z,om4.w};
    const int   pm[4] = {pm4.x,pm4.y,pm4.z,pm4.w};
    #pragma unroll
    for (int j=0;j<4;++j){
      const int pix = pix0 + j;
      const float xm = (float)(pix & 511)*INV511;
      const float ym = (float)(pix >> 9)*INV511;
      const float ep0 = xm + ftanh(a3[j]);       // parts emb
      const float ep1 = ym + ftanh(a4[j]);
      const float eo0 = ep0 + ftanh(a0[j]);      // obj emb
      const float eo1 = ep1 + ftanh(a1[j]);
      const int lio = om[j] - 1;                 // 0..7 when obj fg
      const int lip = pm[j] - 1;                 // 0..15 when parts fg
      const float so = fsig(d6[j]);
      const float sp = fsig(d7[j]);
      float pwo = 0.f, pwp = 0.f;
      #pragma unroll
      for (int i=0;i<NOBJ;++i){
        const float dx = eo0-cx[i], dy = eo1-cy[i];
        const float p = fexp2(aa[i]*(dx*dx + dy*dy));
        int ib = (int)(p * (float)KB); if (ib > KB-1) ib = KB-1;
        const bool lab = (lio == i);
        if (lab) pwo = p;
        atomicAdd(&h[i*KB + (lab ? (KB-1-ib) : ib)], lab ? 0x10001u : 1u);
      }
      #pragma unroll
      for (int i=0;i<NPART;++i){
        const int ii = NOBJ + i;
        const float dx = ep0-cx[ii], dy = ep1-cy[ii];
        const float p = fexp2(aa[ii]*(dx*dx + dy*dy));
        int ib = (int)(p * (float)KB); if (ib > KB-1) ib = KB-1;
        const bool lab = (lip == i);
        if (lab) pwp = p;
        atomicAdd(&h[ii*KB + (lab ? (KB-1-ib) : ib)], lab ? 0x10001u : 1u);
      }
      const float dso = (lio >= 0) ? (so - pwo) : so;   // bg: label!=1 <=> inst==0
      const float dsp = (lip >= 0) ? (sp - pwp) : sp;
      sl += dso*dso + dsp*dsp;
    }
  }
  for (int off=32; off>0; off>>=1) sl += __shfl_down(sl, off);
  if ((tid & 63)==0) atomicAdd(&ssl, sl);
  __syncthreads();
  unsigned* dst = part + ((size_t)img*NINST*Cn + chunk)*KB;
  for (int i = tid; i < NINST*KB; i += 256){
    const int hi = i >> 8;
    const int bin = i & (KB-1);
    dst[(size_t)hi*Cn*KB + bin] = h[i];
  }
  if (tid == 0) atomicAdd(out, ssl * (1.0f/((float)NPIX*BATCH)));
}

// grid (B*NINST), KB thr: thread t owns bin t; coalesced Cn-sum (unrolled), block scan, loss.
__global__ __launch_bounds__(KB) void k_lovasz(
    const unsigned* __restrict__ part, const float* __restrict__ accum,
    float* __restrict__ out, int Cn){
  __shared__ float sc[KB], sg[KB];
  __shared__ float wt[16];
  __shared__ float lsum[8];
  const int blk = blockIdx.x;            // == img*NINST + inst
  const int inst = blk % NINST;
  const float gts = accum[blk*5];
  if (gts < 0.5f) return;                // block-uniform exit
  const int t = threadIdx.x;
  const unsigned* pb = part + (size_t)blk*Cn*KB;
  unsigned cnt=0u, fg=0u;
  #pragma unroll 16
  for (int c=0;c<Cn;++c){ const unsigned w = pb[(size_t)c*KB + t]; cnt += w & 0xFFFFu; fg += w >> 16; }
  sc[KB-1-t] = (float)cnt; sg[KB-1-t] = (float)fg;   // descending-error order
  __syncthreads();
  const float c = sc[t], g = sg[t];
  float ic = c, ig = g;
  for (int off=1; off<64; off<<=1){
    const float tc = __shfl_up(ic, off); const float tg = __shfl_up(ig, off);
    if ((t & 63) >= off){ ic += tc; ig += tg; }
  }
  const int wid = t >> 6, lane = t & 63;
  if (lane == 63){ wt[wid] = ic; wt[8+wid] = ig; }
  __syncthreads();
  float offc = 0.f, offg = 0.f;
  for (int w2=0; w2<wid; ++w2){ offc += wt[w2]; offg += wt[8+w2]; }
  const float C1 = offc + ic, G1 = offg + ig, C0 = C1 - c, G0 = G1 - g;
  float l = 0.f;
  if (c > 0.f){
    const int bin = KB-1-t;
    const float e = (bin + 0.5f)*(2.0f/KB);
    const float jb = 1.f - (gts-G0)/(gts + C0 - G0);
    const float ja = 1.f - (gts-G1)/(gts + C1 - G1);
    l = e*(ja - jb);
  }
  for (int off=32; off>0; off>>=1) l += __shfl_down(l, off);
  if (lane == 0) lsum[wid] = l;
  __syncthreads();
  if (t == 0){
    float tot = 0.f;
    #pragma unroll
    for (int w2=0; w2<(KB/64); ++w2) tot += lsum[w2];
    const float wN = (inst < NOBJ) ? 8.f : 16.f;
    atomicAdd(out, tot * (1.0f/(wN*BATCH)));
  }
}

extern "C" void kernel_launch(void* const* d_in, const int* in_sizes, int n_in,
                              void* d_out, int out_size, void* d_ws, size_t ws_size,
                              hipStream_t stream){
  (void)in_sizes; (void)n_in; (void)out_size;
  const float* pred       = (const float*)d_in[0];
  const int*   obj_inst   = (const int*)d_in[1];
  const int*   parts_inst = (const int*)d_in[3];
  float* out = (float*)d_out;

  const size_t need256 = (size_t)BATCH*NINST*256*KB*4 + 8192;
  const int Cn = (ws_size >= need256) ? 256 : 64;
  unsigned* part = (unsigned*)d_ws;
  const size_t partWords = (size_t)BATCH*NINST*Cn*KB;
  float* accum  = (float*)((unsigned*)d_ws + partWords);

  hipLaunchKernelGGL(k_zero, dim3(1), dim3(512), 0, stream, accum, out);
  hipLaunchKernelGGL(k_reduce, dim3(NPIX/2048, BATCH), dim3(256), 0, stream,
                     pred, obj_inst, parts_inst, accum);
  hipLaunchKernelGGL(k_main, dim3(Cn, BATCH), dim3(256), 0, stream,
                     pred, obj_inst, parts_inst, accum, part, out, Cn);
  hipLaunchKernelGGL(k_lovasz, dim3(BATCH*NINST), dim3(KB), 0, stream, part, accum, out, Cn);
}

// Round 14
// 123.421 us; speedup vs baseline: 3.4248x; 1.0724x over previous
//
#include <hip/hip_runtime.h>

#define BATCH 4
#define NPIX (512*512)
#define NOBJ 8
#define NPART 16
#define NINST 24
#define KB 256
#define L2E 1.44269504f
#define INV511 (1.0f/511.0f)

__device__ __forceinline__ float fexp2(float x){ return __builtin_amdgcn_exp2f(x); }
__device__ __forceinline__ float frcp(float x){ return __builtin_amdgcn_rcpf(x); }
__device__ __forceinline__ float ftanh(float x){ return 1.f - 2.f*frcp(fexp2(2.f*L2E*x) + 1.f); }
__device__ __forceinline__ float fsig(float x){ return frcp(1.f + fexp2(-L2E*x)); }

// ws: [0, B*24*Cn*KB) u32 partial hists packed (cnt | fg<<16), layout [instG][Cn][KB]
//     then accum f32 [B][24][5] (cnt, sx, sy, ssig, ssig2)

__global__ void k_zero(float* __restrict__ acc, float* __restrict__ out){
  const int i = threadIdx.x;
  if (i < BATCH*NINST*5) acc[i] = 0.f;
  if (i == 0) out[0] = 0.f;
}

// grid (NPIX/4096, BATCH), 256 thr, 16 px/thread vec4 (run-combined LDS atomics).
__global__ __launch_bounds__(256) void k_reduce(
    const float* __restrict__ pred, const int* __restrict__ obj_inst,
    const int* __restrict__ parts_inst, float* __restrict__ accum){
  __shared__ float acc[NINST*5];
  const int tid = threadIdx.x;
  if (tid < NINST*5) acc[tid] = 0.f;
  __syncthreads();
  const int img = blockIdx.y;
  const float* predb = pred + (size_t)img*8*NPIX;
  const int pix0 = blockIdx.x*4096 + tid*16;
  const int v = pix0 >> 2;
  const int*   obase = obj_inst   + (size_t)img*NPIX;
  const int*   pbase = parts_inst + (size_t)img*NPIX;
  int   oid[16], pid[16];
  float so[16], sp[16];
  #pragma unroll
  for (int q=0;q<4;++q){
    const int4 a = ((const int4*)obase)[v+q];
    oid[4*q]=a.x; oid[4*q+1]=a.y; oid[4*q+2]=a.z; oid[4*q+3]=a.w;
  }
  #pragma unroll
  for (int q=0;q<4;++q){
    const int4 a = ((const int4*)pbase)[v+q];
    pid[4*q]=a.x; pid[4*q+1]=a.y; pid[4*q+2]=a.z; pid[4*q+3]=a.w;
  }
  #pragma unroll
  for (int q=0;q<4;++q){
    const float4 a = ((const float4*)(predb+2*NPIX))[v+q];
    so[4*q]=a.x; so[4*q+1]=a.y; so[4*q+2]=a.z; so[4*q+3]=a.w;
  }
  #pragma unroll
  for (int q=0;q<4;++q){
    const float4 a = ((const float4*)(predb+5*NPIX))[v+q];
    sp[4*q]=a.x; sp[4*q+1]=a.y; sp[4*q+2]=a.z; sp[4*q+3]=a.w;
  }
  float c0=0,c1=0,c2=0,c3=0,c4=0; int cur=-1;
#define FLUSH_ACC() if (cur>=0){ float* a=&acc[cur*5]; atomicAdd(a,c0); atomicAdd(a+1,c1); \
    atomicAdd(a+2,c2); atomicAdd(a+3,c3); atomicAdd(a+4,c4); }
  #pragma unroll
  for (int j=0;j<16;++j){
    const int id = oid[j];
    if (id>=1 && id<=NOBJ){
      const int slot = id-1;
      if (slot != cur){ FLUSH_ACC(); cur=slot; c0=c1=c2=c3=c4=0.f; }
      const int pix = pix0+j;
      c0 += 1.f; c1 += (float)(pix & 511)*INV511; c2 += (float)(pix >> 9)*INV511;
      const float s=so[j]; c3 += s; c4 += s*s;
    }
  }
  FLUSH_ACC();
  c0=c1=c2=c3=c4=0.f; cur=-1;
  #pragma unroll
  for (int j=0;j<16;++j){
    const int id = pid[j];
    if (id>=1 && id<=NPART){
      const int slot = NOBJ + id-1;
      if (slot != cur){ FLUSH_ACC(); cur=slot; c0=c1=c2=c3=c4=0.f; }
      const int pix = pix0+j;
      c0 += 1.f; c1 += (float)(pix & 511)*INV511; c2 += (float)(pix >> 9)*INV511;
      const float s=sp[j]; c3 += s; c4 += s*s;
    }
  }
  FLUSH_ACC();
#undef FLUSH_ACC
  __syncthreads();
  if (tid < NINST*5 && acc[tid] != 0.f) atomicAdd(&accum[img*NINST*5 + tid], acc[tid]);
}

// Fused single-pass: grid (Cn, B), 256 thr, 4 px/thread/iter, all 24 instances.
// Inlines params (from accum), var term (chunk==0), both seed losses.
__global__ __launch_bounds__(256) void k_main(
    const float* __restrict__ pred, const int* __restrict__ obj_inst,
    const int* __restrict__ parts_inst, const float* __restrict__ accum,
    unsigned* __restrict__ part, float* __restrict__ out, int Cn){
  __shared__ unsigned h[NINST*KB];       // 24KB
  __shared__ float pz[NINST*3];          // cx, cy, aa
  __shared__ float ssl;
  const int tid = threadIdx.x;
  for (int i = tid; i < NINST*KB; i += 256) h[i] = 0u;
  if (tid == 0) ssl = 0.f;
  const int chunk = blockIdx.x, img = blockIdx.y;
  if (tid < NINST){
    const float* a = accum + (img*NINST + tid)*5;
    const float cnt = a[0];
    float cx=0.f, cy=0.f, aa=-0.72134752f, var=0.f;
    if (cnt > 0.5f){
      const float inv = 1.0f/cnt;
      cx = a[1]*inv; cy = a[2]*inv;
      const float s = a[3]*inv;
      var = a[4]*inv - s*s; if (var < 0.f) var = 0.f;
      aa = -0.72134752f*expf(5.5f*s);    // -0.5*log2(e)*l11
    }
    pz[tid*3]=cx; pz[tid*3+1]=cy; pz[tid*3+2]=aa;
    if (chunk == 0 && cnt > 0.5f){
      const float wN = (tid < NOBJ) ? 8.f : 16.f;
      atomicAdd(out, var * (10.0f/(wN*BATCH)));
    }
  }
  __syncthreads();
  float cx[NINST], cy[NINST], aa[NINST];
  #pragma unroll
  for (int i=0;i<NINST;++i){ cx[i]=pz[i*3]; cy[i]=pz[i*3+1]; aa[i]=pz[i*3+2]; }
  const float* predb = pred + (size_t)img*8*NPIX;
  const int* omap = obj_inst   + (size_t)img*NPIX;
  const int* pmap = parts_inst + (size_t)img*NPIX;
  float sl = 0.f;
  const int chunkpix = NPIX / Cn;
  const int base = chunk * chunkpix;
  const int iters = chunkpix >> 10;      // 256 thr * 4 px
  for (int it=0; it<iters; ++it){
    const int pix0 = base + (it<<10) + tid*4;
    const int v = pix0 >> 2;
    const float4 t0 = ((const float4*)(predb + 0*NPIX))[v];
    const float4 t1 = ((const float4*)(predb + 1*NPIX))[v];
    const float4 t3 = ((const float4*)(predb + 3*NPIX))[v];
    const float4 t4 = ((const float4*)(predb + 4*NPIX))[v];
    const float4 s6 = ((const float4*)(predb + 6*NPIX))[v];
    const float4 s7 = ((const float4*)(predb + 7*NPIX))[v];
    const int4   om4 = ((const int4*)omap)[v];
    const int4   pm4 = ((const int4*)pmap)[v];
    const float a0[4] = {t0.x,t0.y,t0.z,t0.w};
    const float a1[4] = {t1.x,t1.y,t1.z,t1.w};
    const float a3[4] = {t3.x,t3.y,t3.z,t3.w};
    const float a4[4] = {t4.x,t4.y,t4.z,t4.w};
    const float d6[4] = {s6.x,s6.y,s6.z,s6.w};
    const float d7[4] = {s7.x,s7.y,s7.z,s7.w};
    const int   om[4] = {om4.x,om4.y,om4.z,om4.w};
    const int   pm[4] = {pm4.x,pm4.y,pm4.z,pm4.w};
    #pragma unroll
    for (int j=0;j<4;++j){
      const int pix = pix0 + j;
      const float xm = (float)(pix & 511)*INV511;
      const float ym = (float)(pix >> 9)*INV511;
      const float ep0 = xm + ftanh(a3[j]);       // parts emb
      const float ep1 = ym + ftanh(a4[j]);
      const float eo0 = ep0 + ftanh(a0[j]);      // obj emb
      const float eo1 = ep1 + ftanh(a1[j]);
      const int lio = om[j] - 1;                 // 0..7 when obj fg
      const int lip = pm[j] - 1;                 // 0..15 when parts fg
      const float so = fsig(d6[j]);
      const float sp = fsig(d7[j]);
      float pwo = 0.f, pwp = 0.f;
      #pragma unroll
      for (int i=0;i<NOBJ;++i){
        const float dx = eo0-cx[i], dy = eo1-cy[i];
        const float p = fexp2(aa[i]*(dx*dx + dy*dy));
        int ib = (int)(p * (float)KB); if (ib > KB-1) ib = KB-1;
        const bool lab = (lio == i);
        if (lab) pwo = p;
        atomicAdd(&h[i*KB + (lab ? (KB-1-ib) : ib)], lab ? 0x10001u : 1u);
      }
      #pragma unroll
      for (int i=0;i<NPART;++i){
        const int ii = NOBJ + i;
        const float dx = ep0-cx[ii], dy = ep1-cy[ii];
        const float p = fexp2(aa[ii]*(dx*dx + dy*dy));
        int ib = (int)(p * (float)KB); if (ib > KB-1) ib = KB-1;
        const bool lab = (lip == i);
        if (lab) pwp = p;
        atomicAdd(&h[ii*KB + (lab ? (KB-1-ib) : ib)], lab ? 0x10001u : 1u);
      }
      const float dso = (lio >= 0) ? (so - pwo) : so;   // bg: label!=1 <=> inst==0
      const float dsp = (lip >= 0) ? (sp - pwp) : sp;
      sl += dso*dso + dsp*dsp;
    }
  }
  for (int off=32; off>0; off>>=1) sl += __shfl_down(sl, off);
  if ((tid & 63)==0) atomicAdd(&ssl, sl);
  __syncthreads();
  unsigned* dst = part + ((size_t)img*NINST*Cn + chunk)*KB;
  for (int i = tid; i < NINST*KB; i += 256){
    const int hi = i >> 8;
    const int bin = i & (KB-1);
    dst[(size_t)hi*Cn*KB + bin] = h[i];
  }
  if (tid == 0) atomicAdd(out, ssl * (1.0f/((float)NPIX*BATCH)));
}

// grid (B*NINST), KB thr: thread t owns bin t; coalesced Cn-sum (unrolled), block scan, loss.
__global__ __launch_bounds__(KB) void k_lovasz(
    const unsigned* __restrict__ part, const float* __restrict__ accum,
    float* __restrict__ out, int Cn){
  __shared__ float sc[KB], sg[KB];
  __shared__ float wt[16];
  __shared__ float lsum[8];
  const int blk = blockIdx.x;            // == img*NINST + inst
  const int inst = blk % NINST;
  const float gts = accum[blk*5];
  if (gts < 0.5f) return;                // block-uniform exit
  const int t = threadIdx.x;
  const unsigned* pb = part + (size_t)blk*Cn*KB;
  unsigned cnt=0u, fg=0u;
  #pragma unroll 16
  for (int c=0;c<Cn;++c){ const unsigned w = pb[(size_t)c*KB + t]; cnt += w & 0xFFFFu; fg += w >> 16; }
  sc[KB-1-t] = (float)cnt; sg[KB-1-t] = (float)fg;   // descending-error order
  __syncthreads();
  const float c = sc[t], g = sg[t];
  float ic = c, ig = g;
  for (int off=1; off<64; off<<=1){
    const float tc = __shfl_up(ic, off); const float tg = __shfl_up(ig, off);
    if ((t & 63) >= off){ ic += tc; ig += tg; }
  }
  const int wid = t >> 6, lane = t & 63;
  if (lane == 63){ wt[wid] = ic; wt[8+wid] = ig; }
  __syncthreads();
  float offc = 0.f, offg = 0.f;
  for (int w2=0; w2<wid; ++w2){ offc += wt[w2]; offg += wt[8+w2]; }
  const float C1 = offc + ic, G1 = offg + ig, C0 = C1 - c, G0 = G1 - g;
  float l = 0.f;
  if (c > 0.f){
    const int bin = KB-1-t;
    const float e = (bin + 0.5f)*(2.0f/KB);
    const float jb = 1.f - (gts-G0)/(gts + C0 - G0);
    const float ja = 1.f - (gts-G1)/(gts + C1 - G1);
    l = e*(ja - jb);
  }
  for (int off=32; off>0; off>>=1) l += __shfl_down(l, off);
  if (lane == 0) lsum[wid] = l;
  __syncthreads();
  if (t == 0){
    float tot = 0.f;
    #pragma unroll
    for (int w2=0; w2<(KB/64); ++w2) tot += lsum[w2];
    const float wN = (inst < NOBJ) ? 8.f : 16.f;
    atomicAdd(out, tot * (1.0f/(wN*BATCH)));
  }
}

extern "C" void kernel_launch(void* const* d_in, const int* in_sizes, int n_in,
                              void* d_out, int out_size, void* d_ws, size_t ws_size,
                              hipStream_t stream){
  (void)in_sizes; (void)n_in; (void)out_size;
  const float* pred       = (const float*)d_in[0];
  const int*   obj_inst   = (const int*)d_in[1];
  const int*   parts_inst = (const int*)d_in[3];
  float* out = (float*)d_out;

  const size_t need128 = (size_t)BATCH*NINST*128*KB*4 + 8192;
  const int Cn = (ws_size >= need128) ? 128 : 64;
  unsigned* part = (unsigned*)d_ws;
  const size_t partWords = (size_t)BATCH*NINST*Cn*KB;
  float* accum  = (float*)((unsigned*)d_ws + partWords);

  hipLaunchKernelGGL(k_zero, dim3(1), dim3(512), 0, stream, accum, out);
  hipLaunchKernelGGL(k_reduce, dim3(NPIX/4096, BATCH), dim3(256), 0, stream,
                     pred, obj_inst, parts_inst, accum);
  hipLaunchKernelGGL(k_main, dim3(Cn, BATCH), dim3(256), 0, stream,
                     pred, obj_inst, parts_inst, accum, part, out, Cn);
  hipLaunchKernelGGL(k_lovasz, dim3(BATCH*NINST), dim3(KB), 0, stream, part, accum, out, Cn);
}